// Round 21
// baseline (1502.347 us; speedup 1.0000x reference)
//
#include <hip/hip_runtime.h>

typedef _Float16 half8 __attribute__((ext_vector_type(8)));
typedef float f32x4 __attribute__((ext_vector_type(4)));
typedef unsigned uint4v __attribute__((ext_vector_type(4)));

#define BB 64
#define SS 512
#define DD 512
#define HH 1024
#define KK 1536
#define GG 4               // independent batch-row groups (rings)
#define RR 16              // rows per group
#define PKST 48            // 16B packets per producer region (3 per row)

#define MFMA(a, b, c) __builtin_amdgcn_mfma_f32_16x16x32_f16(a, b, c, 0, 0, 0)

// x-region of Wp: fragment permutation; h-region: identity on both operands
// (the shared permutation cancels inside the MFMA dot product).
__device__ __host__ __forceinline__ int kperm(int k) {
  int blk = k >> 5, r = k & 31;
  return (blk << 5) | (((r >> 2) & 3) << 3) | ((r >> 4) << 2) | (r & 3);
}

// Pack weights: Wp[p][k'] fp16, p = b*80 + tile*16 + c  (tile: 0=g,1=r,2=z,3=i_n,4=h_n)
__global__ void prep_w(const float* __restrict__ Wg, const float* __restrict__ Wih,
                       const float* __restrict__ Whh, _Float16* __restrict__ Wp) {
  int p = blockIdx.x;
  int b = p / 80, rem = p % 80, t = rem >> 4, c = rem & 15;
  int j = b * 16 + c;
  for (int pass = 0; pass < 6; ++pass) {
    int k = pass * 256 + threadIdx.x;
    float v;
    if (t == 0)      v = Wg[k * HH + j];
    else if (t == 1) v = (k < DD) ? Wih[k * 3 * HH + j]          : Whh[(k - DD) * 3 * HH + j];
    else if (t == 2) v = (k < DD) ? Wih[k * 3 * HH + HH + j]     : Whh[(k - DD) * 3 * HH + HH + j];
    else if (t == 3) v = (k < DD) ? Wih[k * 3 * HH + 2 * HH + j] : 0.f;
    else             v = (k < DD) ? 0.f : Whh[(k - DD) * 3 * HH + 2 * HH + j];
    int pos = (k < DD) ? kperm(k) : k;      // x: kperm'd, h: identity
    Wp[(size_t)p * KK + pos] = (_Float16)v;
  }
}

// Xh[t][sg][row 0..63][lkg][8]: fp16 x in fragment-ready order
__global__ void prep_xh(const float* __restrict__ x, _Float16* __restrict__ Xh) {
  int t = blockIdx.x, sg = blockIdx.y;
  int row = threadIdx.x >> 2, lkg = threadIdx.x & 3;
  const float* xp = x + ((size_t)row * SS + t) * DD + sg * 32 + lkg * 4;
  half8 hv;
#pragma unroll
  for (int j = 0; j < 4; ++j) { hv[j] = (_Float16)xp[j]; hv[4 + j] = (_Float16)xp[16 + j]; }
  *(half8*)(Xh + ((((size_t)t * 16 + sg) * 64 + row) * 4 + lkg) * 8) = hv;
}

#define WAITV(lit) do { asm volatile("s_waitcnt vmcnt(" lit ")" ::: "memory"); \
                        __builtin_amdgcn_sched_barrier(0); } while (0)

// ---- tagged-packet H exchange (r20 + xpref/pub decoupling) ----------------
// Region (group g, parity b, producer cb) = PKST x 16B packets; per row r:
// pkt3r={c0..5,tag} 3r+1={c6..11,tag} 3r+2={c12..15,0,tag}. Publish = 48
// fire-and-forget coalesced stores; consumer's load IS the poll (16B
// single-copy atomic). Shared-middle addressing (r20): L1 loads pkt
// 3r+(odd?2:0), L2 loads pkt 3r+1 on ALL lanes (coalescer merges).
// r21's ONE change: xpref is issued AFTER the packet batches, so the
// counted waits (now 8/6/4/2) no longer gate the first tag check on the
// xpref latency or the publish-store ack (vmcnt retires in order; pub is
// older than A so it retires before A anyway). Loop-top per-wave drain:
// w<4 WAITV("1") (xpref retired, pub ack may stay outstanding), w>=4
// WAITV("0"). xpref gets the whole reduce/epilogue window to land.
// Fragment dwords: even={P0.x,P0.y,P0.z,P1.x}; odd={P1.y,P1.z,P0.x,P0.y}.

__device__ __forceinline__ void issue_pk2(const uint4v* ap0, const uint4v* ap1,
                                          uint4v& P0, uint4v& P1) {
  asm volatile("global_load_dwordx4 %0, %2, off sc0 sc1\n\t"
               "global_load_dwordx4 %1, %3, off sc0 sc1"
               : "=&v"(P0), "=&v"(P1) : "v"(ap0), "v"(ap1) : "memory");
}

__device__ __forceinline__ int tags_ok2(const uint4v& P0, const uint4v& P1, unsigned want) {
  return __all((int)(((P0[3] ^ want) | (P1[3] ^ want)) == 0));
}

// Per-batch retry (rare): reissue just this batch, drain, recheck.
#define RETRY2(P0a, P1a, ap0_, ap1_) do { \
    if (!tags_ok2(P0a, P1a, want)) { \
      do { issue_pk2(ap0_, ap1_, P0a, P1a); WAITV("0"); } \
      while (!tags_ok2(P0a, P1a, want)); } } while (0)

__global__ __launch_bounds__(512, 2) void rnn_seq(
    const _Float16* __restrict__ Xh, const _Float16* __restrict__ Wp,
    const float* __restrict__ bg, const float* __restrict__ bih,
    const float* __restrict__ bhh, float* __restrict__ out,
    uint4v* __restrict__ Pk) {
  const int blk = blockIdx.x;          // 0..255
  const int g = blk >> 6;              // batch-row group 0..3 (rows g*16..+16)
  const int cb = blk & 63;             // column block 0..63
  const int tid = threadIdx.x;
  const int w = tid >> 6;              // wave 0..7 (K-split)
  const int lane = tid & 63;
  const int lrow = lane & 15;
  const int lkg = lane >> 4;
  const int phalf = lkg >> 1;          // which producer of the k-step pair
  const int odd = lkg & 1;             // which 8-col half
  const int wk = (w + cb) & 7;         // rotated h k-slice (r14 hotspot fix)
  const int pk0 = 3 * lrow + (odd ? 2 : 0);  // L1 packet index
  const int pk1 = 3 * lrow + 1;              // L2 packet index (shared)

  __shared__ float Red[8][80][18];               // 46,080 B (8 slabs, no add phase)
  __shared__ alignas(16) _Float16 Xstage[16 * 512];  // 16,384 B

  const int ej = tid & 15;
  const int rr = (tid >> 4) & 15;
  const int ghcol = cb * 16 + ej;
  const float bg_b  = bg[ghcol];
  const float br_b  = bih[ghcol] + bhh[ghcol];
  const float bz_b  = bih[HH + ghcol] + bhh[HH + ghcol];
  const float bin_b = bih[2 * HH + ghcol];
  const float bhn_b = bhh[2 * HH + ghcol];
  float hreg = 0.f;

  // producer block index for batch kk: p = pbase + kk*2
  const int pbase = wk * 8 + phalf;

  // register-resident weights (24 half8 = 96 VGPR); h-side uses wk
  half8 bx[3][2], b3[2], bh[3][4], b4[4];
#pragma unroll
  for (int tt = 0; tt < 3; ++tt)
#pragma unroll
    for (int kk = 0; kk < 2; ++kk)
      bx[tt][kk] = *(const half8*)(Wp + (size_t)(cb * 80 + tt * 16 + lrow) * KK + (w * 2 + kk) * 32 + lkg * 8);
#pragma unroll
  for (int kk = 0; kk < 2; ++kk)
    b3[kk] = *(const half8*)(Wp + (size_t)(cb * 80 + 48 + lrow) * KK + (w * 2 + kk) * 32 + lkg * 8);
#pragma unroll
  for (int tt = 0; tt < 3; ++tt)
#pragma unroll
    for (int kk = 0; kk < 4; ++kk)
      bh[tt][kk] = *(const half8*)(Wp + (size_t)(cb * 80 + tt * 16 + lrow) * KK + (16 + wk * 4 + kk) * 32 + lkg * 8);
#pragma unroll
  for (int kk = 0; kk < 4; ++kk)
    b4[kk] = *(const half8*)(Wp + (size_t)(cb * 80 + 64 + lrow) * KK + (16 + wk * 4 + kk) * 32 + lkg * 8);

  // prefetch Xstage(t=0)
#pragma unroll
  for (int kk = 0; kk < 2; ++kk) {
    const _Float16* gsrc = Xh + ((((size_t)0 * 16 + (w * 2 + kk)) * 64 + (g * RR + lrow)) * 4 + lkg) * 8;
    __builtin_amdgcn_global_load_lds(
        (const __attribute__((address_space(1))) void*)gsrc,
        (__attribute__((address_space(3))) void*)(Xstage + (w * 2 + kk) * 512), 16, 0, 0);
  }
  WAITV("0");

  for (int t = 0; t < SS; ++t) {
    const uint4v* Rg = Pk + (size_t)((g * 2 + (t & 1)) * 64) * PKST;
    uint4v* Rn = Pk + (size_t)((g * 2 + ((t + 1) & 1)) * 64) * PKST;
    const unsigned want = (unsigned)t;
    const uint4v* apA0 = Rg + (size_t)(pbase + 0) * PKST + pk0;
    const uint4v* apA1 = Rg + (size_t)(pbase + 0) * PKST + pk1;
    const uint4v* apB0 = Rg + (size_t)(pbase + 2) * PKST + pk0;
    const uint4v* apB1 = Rg + (size_t)(pbase + 2) * PKST + pk1;
    const uint4v* apC0 = Rg + (size_t)(pbase + 4) * PKST + pk0;
    const uint4v* apC1 = Rg + (size_t)(pbase + 4) * PKST + pk1;
    const uint4v* apD0 = Rg + (size_t)(pbase + 6) * PKST + pk0;
    const uint4v* apD1 = Rg + (size_t)(pbase + 6) * PKST + pk1;

    // ---- loop-top drain: xpref(t-1) must be retired before x ds_reads.
    // w<4 allow the (older-issue? no -- younger) pub store to remain
    // outstanding: queue from iter t-1 is [xpref:2][pub:1], in-order
    // retirement means vmcnt(1) => both xpref retired, pub may be in
    // flight (its ack never blocks us). w>=4 have no pub: vmcnt(0) free.
    if (t > 0) {
      if (w < 4) WAITV("1");
      else       WAITV("0");
    }

    f32x4 zz = {0.f, 0.f, 0.f, 0.f};
    f32x4 acc[5];
#pragma unroll
    for (int tt = 0; tt < 5; ++tt) acc[tt] = zz;

    // ---- x ds_reads into registers ----
    half8 xfr[2];
#pragma unroll
    for (int kk = 0; kk < 2; ++kk)
      xfr[kk] = *(const half8*)(Xstage + (w * 2 + kk) * 512 + lane * 8);
    asm volatile("s_waitcnt lgkmcnt(0)" ::: "memory");   // reads retired (WAR)
    __builtin_amdgcn_sched_barrier(0);

    // ---- issue all 4 packet batches FIRST; RTs overlap x-MFMA.
    // Queue/wave after this block: [pub?:1][A:2][B:2][C:2][D:2]
    uint4v A0, A1, B0, B1, C0, C1, D0, D1;
    issue_pk2(apA0, apA1, A0, A1);
    issue_pk2(apB0, apB1, B0, B1);
    issue_pk2(apC0, apC1, C0, C1);
    issue_pk2(apD0, apD1, D0, D1);

    // ---- xpref(t+1) AFTER the batches (r21 change): its latency is no
    // longer on the A..D wait path; it drains during reduce/epilogue.
    {
      const int tn = (t + 1 < SS) ? t + 1 : t;
#pragma unroll
      for (int kk = 0; kk < 2; ++kk) {
        const _Float16* gsrc = Xh + ((((size_t)tn * 16 + (w * 2 + kk)) * 64 + (g * RR + lrow)) * 4 + lkg) * 8;
        __builtin_amdgcn_global_load_lds(
            (const __attribute__((address_space(1))) void*)gsrc,
            (__attribute__((address_space(3))) void*)(Xstage + (w * 2 + kk) * 512), 16, 0, 0);
      }
    }

    // ---- x-MFMA from registers (overlaps packet round trips) ----
#pragma unroll
    for (int kk = 0; kk < 2; ++kk) {
      acc[0] = MFMA(xfr[kk], bx[0][kk], acc[0]);
      acc[1] = MFMA(xfr[kk], bx[1][kk], acc[1]);
      acc[2] = MFMA(xfr[kk], bx[2][kk], acc[2]);
      acc[3] = MFMA(xfr[kk], b3[kk], acc[3]);
    }

    // ---- h-MFMA: counted waits 8/6/4/2 (= ops issued after target batch:
    // B/C/D + xpref). Older pub retires before A by in-order rule. D's wait
    // leaves xpref in flight (drained at next loop top).
    // fv: even={P0.x,P0.y,P0.z,P1.x}; odd={P1.y,P1.z,P0.x,P0.y}
    WAITV("8"); RETRY2(A0, A1, apA0, apA1);
    {
      uint4v fv; fv[0] = odd ? A1[1] : A0[0]; fv[1] = odd ? A1[2] : A0[1];
      fv[2] = odd ? A0[0] : A0[2];     fv[3] = odd ? A0[1] : A1[0];
      half8 af = __builtin_bit_cast(half8, fv);
      acc[0] = MFMA(af, bh[0][0], acc[0]); acc[1] = MFMA(af, bh[1][0], acc[1]);
      acc[2] = MFMA(af, bh[2][0], acc[2]); acc[4] = MFMA(af, b4[0], acc[4]);
    }
    WAITV("6"); RETRY2(B0, B1, apB0, apB1);
    {
      uint4v fv; fv[0] = odd ? B1[1] : B0[0]; fv[1] = odd ? B1[2] : B0[1];
      fv[2] = odd ? B0[0] : B0[2];     fv[3] = odd ? B0[1] : B1[0];
      half8 af = __builtin_bit_cast(half8, fv);
      acc[0] = MFMA(af, bh[0][1], acc[0]); acc[1] = MFMA(af, bh[1][1], acc[1]);
      acc[2] = MFMA(af, bh[2][1], acc[2]); acc[4] = MFMA(af, b4[1], acc[4]);
    }
    WAITV("4"); RETRY2(C0, C1, apC0, apC1);
    {
      uint4v fv; fv[0] = odd ? C1[1] : C0[0]; fv[1] = odd ? C1[2] : C0[1];
      fv[2] = odd ? C0[0] : C0[2];     fv[3] = odd ? C0[1] : C1[0];
      half8 af = __builtin_bit_cast(half8, fv);
      acc[0] = MFMA(af, bh[0][2], acc[0]); acc[1] = MFMA(af, bh[1][2], acc[1]);
      acc[2] = MFMA(af, bh[2][2], acc[2]); acc[4] = MFMA(af, b4[2], acc[4]);
    }
    WAITV("2"); RETRY2(D0, D1, apD0, apD1);
    {
      uint4v fv; fv[0] = odd ? D1[1] : D0[0]; fv[1] = odd ? D1[2] : D0[1];
      fv[2] = odd ? D0[0] : D0[2];     fv[3] = odd ? D0[1] : D1[0];
      half8 af = __builtin_bit_cast(half8, fv);
      acc[0] = MFMA(af, bh[0][3], acc[0]); acc[1] = MFMA(af, bh[1][3], acc[1]);
      acc[2] = MFMA(af, bh[2][3], acc[2]); acc[4] = MFMA(af, b4[3], acc[4]);
    }

    // ---- 8-slab reduce: every wave writes its partials; ONE barrier ----
#pragma unroll
    for (int tt = 0; tt < 5; ++tt)
      *(f32x4*)&Red[w][tt * 16 + lrow][lkg * 4] = acc[tt];
    __syncthreads();

    // ---- fused epilogue + in-register packet publish (waves 0-3) ----
    if (tid < 256) {
      float s5[5];
#pragma unroll
      for (int g5 = 0; g5 < 5; ++g5) {
        float a = 0.f;
#pragma unroll
        for (int sl = 0; sl < 8; ++sl) a += Red[sl][g5 * 16 + ej][rr];
        s5[g5] = a;
      }
      float g_ = 1.f / (1.f + __expf(-(s5[0] + bg_b)));
      float r_ = 1.f / (1.f + __expf(-(s5[1] + br_b)));
      float z_ = 1.f / (1.f + __expf(-(s5[2] + bz_b)));
      float n_ = tanhf(s5[3] + bin_b + r_ * (s5[4] + bhn_b));
      float h = g_ * ((1.f - z_) * n_ + z_ * hreg);
      hreg = h;
      if (t == SS - 1) {
        out[(size_t)(g * RR + rr) * HH + ghcol] = h;
      } else {
        // pack col-pairs on even lanes, gather 3 dwords per packet into
        // publisher lanes 0..11 (packet w*12+lane), fire-and-forget store.
        unsigned hbits = (unsigned)__builtin_bit_cast(unsigned short, (_Float16)h);
        unsigned nb = (unsigned)__shfl_down((int)hbits, 1);
        int d = (int)(hbits | (nb << 16));          // valid on even cols
        int qp = lane / 3, sseg = lane - qp * 3;    // publisher mapping
        int srcbase = (qp << 4) + sseg * 6;
        int d0 = __builtin_amdgcn_ds_bpermute((srcbase + 0) << 2, d);
        int d1 = __builtin_amdgcn_ds_bpermute((srcbase + 2) << 2, d);
        int d2 = __builtin_amdgcn_ds_bpermute((srcbase + 4) << 2, d);
        if (lane < 12) {
          uint4v pk;
          pk[0] = (unsigned)d0;
          pk[1] = (unsigned)d1;
          pk[2] = (sseg == 2) ? 0u : (unsigned)d2;
          pk[3] = (unsigned)(t + 1);
          uint4v* dst = Rn + (size_t)cb * PKST + (w * 12 + lane);
          asm volatile("global_store_dwordx4 %0, %1, off sc0 sc1" :: "v"(dst), "v"(pk) : "memory");
        }
      }
    }
    __syncthreads();   // Red WAR + holds all waves until publish issued (r18)
  }
}

extern "C" void kernel_launch(void* const* d_in, const int* in_sizes, int n_in,
                              void* d_out, int out_size, void* d_ws, size_t ws_size,
                              hipStream_t stream) {
  const float* x   = (const float*)d_in[0];
  const float* Wg  = (const float*)d_in[1];
  const float* bg  = (const float*)d_in[2];
  const float* Wih = (const float*)d_in[3];
  const float* bih = (const float*)d_in[4];
  const float* Whh = (const float*)d_in[5];
  const float* bhh = (const float*)d_in[6];
  // d_in[7..10] (Wa, ba, Ws, bs) are mathematically dead: softmax over size-1 axis == 1
  float* out = (float*)d_out;

  char* ws = (char*)d_ws;
  _Float16* Wp = (_Float16*)ws;                        // 15,728,640 B
  _Float16* Xh = (_Float16*)(ws + 15728640);           // 33,554,432 B
  uint4v*   Pk = (uint4v*)(ws + 15728640 + 33554432);  // 4*2*64*48*16 = 393,216 B

  // Zero both parities every launch: tag 0 == valid zero h(0) for t=0; a
  // stale tag from a previous replay can never equal want=t>0 after the wipe.
  hipMemsetAsync((void*)Pk, 0, 393216, stream);
  prep_w<<<5120, 256, 0, stream>>>(Wg, Wih, Whh, Wp);
  prep_xh<<<dim3(512, 16), 256, 0, stream>>>(x, Xh);
  rnn_seq<<<256, 512, 0, stream>>>(Xh, Wp, bg, bih, bhh, out, Pk);
}

// Round 22
// 1283.910 us; speedup vs baseline: 1.1701x; 1.1701x over previous
//
#include <hip/hip_runtime.h>

typedef _Float16 half8 __attribute__((ext_vector_type(8)));
typedef float f32x4 __attribute__((ext_vector_type(4)));
typedef unsigned uint4v __attribute__((ext_vector_type(4)));

#define BB 64
#define SS 512
#define DD 512
#define HH 1024
#define KK 1536
#define GG 4               // independent batch-row groups (rings)
#define RR 16              // rows per group
#define PKST 48            // 16B packets per producer region (3 per row)

#define MFMA(a, b, c) __builtin_amdgcn_mfma_f32_16x16x32_f16(a, b, c, 0, 0, 0)

// x-region of Wp: fragment permutation; h-region: identity on both operands
// (the shared permutation cancels inside the MFMA dot product).
__device__ __host__ __forceinline__ int kperm(int k) {
  int blk = k >> 5, r = k & 31;
  return (blk << 5) | (((r >> 2) & 3) << 3) | ((r >> 4) << 2) | (r & 3);
}

// Pack weights: Wp[p][k'] fp16, p = b*80 + tile*16 + c  (tile: 0=g,1=r,2=z,3=i_n,4=h_n)
__global__ void prep_w(const float* __restrict__ Wg, const float* __restrict__ Wih,
                       const float* __restrict__ Whh, _Float16* __restrict__ Wp) {
  int p = blockIdx.x;
  int b = p / 80, rem = p % 80, t = rem >> 4, c = rem & 15;
  int j = b * 16 + c;
  for (int pass = 0; pass < 6; ++pass) {
    int k = pass * 256 + threadIdx.x;
    float v;
    if (t == 0)      v = Wg[k * HH + j];
    else if (t == 1) v = (k < DD) ? Wih[k * 3 * HH + j]          : Whh[(k - DD) * 3 * HH + j];
    else if (t == 2) v = (k < DD) ? Wih[k * 3 * HH + HH + j]     : Whh[(k - DD) * 3 * HH + HH + j];
    else if (t == 3) v = (k < DD) ? Wih[k * 3 * HH + 2 * HH + j] : 0.f;
    else             v = (k < DD) ? 0.f : Whh[(k - DD) * 3 * HH + 2 * HH + j];
    int pos = (k < DD) ? kperm(k) : k;      // x: kperm'd, h: identity
    Wp[(size_t)p * KK + pos] = (_Float16)v;
  }
}

// Xh[t][sg][row 0..63][lkg][8]: fp16 x in fragment-ready order
__global__ void prep_xh(const float* __restrict__ x, _Float16* __restrict__ Xh) {
  int t = blockIdx.x, sg = blockIdx.y;
  int row = threadIdx.x >> 2, lkg = threadIdx.x & 3;
  const float* xp = x + ((size_t)row * SS + t) * DD + sg * 32 + lkg * 4;
  half8 hv;
#pragma unroll
  for (int j = 0; j < 4; ++j) { hv[j] = (_Float16)xp[j]; hv[4 + j] = (_Float16)xp[16 + j]; }
  *(half8*)(Xh + ((((size_t)t * 16 + sg) * 64 + row) * 4 + lkg) * 8) = hv;
}

#define WAITV(lit) do { asm volatile("s_waitcnt vmcnt(" lit ")" ::: "memory"); \
                        __builtin_amdgcn_sched_barrier(0); } while (0)

// ---- tagged-packet H exchange (r20 measured optimum, restored) ------------
// Region (group g, parity b, producer cb) = PKST x 16B packets; per row r:
// pkt3r={c0..5,tag} 3r+1={c6..11,tag} 3r+2={c12..15,0,tag}. Publish = 48
// fire-and-forget coalesced stores; consumer's load IS the poll (16B
// single-copy atomic, r6-r8). Shared-middle addressing: L1 loads pkt
// 3r+(odd?2:0), L2 loads pkt 3r+1 on ALL lanes (coalescer merges; -25%
// exchange requests). xpref is issued BEFORE the packet batches: its
// latency inside the A-wait acts as a grace period that lets producer
// stores land before the first tag check (r21 proved removing it causes
// early-check retries). Counted waits 6/4/2/0.
// Fragment dwords: even={P0.x,P0.y,P0.z,P1.x}; odd={P1.y,P1.z,P0.x,P0.y}.

__device__ __forceinline__ void issue_pk2(const uint4v* ap0, const uint4v* ap1,
                                          uint4v& P0, uint4v& P1) {
  asm volatile("global_load_dwordx4 %0, %2, off sc0 sc1\n\t"
               "global_load_dwordx4 %1, %3, off sc0 sc1"
               : "=&v"(P0), "=&v"(P1) : "v"(ap0), "v"(ap1) : "memory");
}

__device__ __forceinline__ int tags_ok2(const uint4v& P0, const uint4v& P1, unsigned want) {
  return __all((int)(((P0[3] ^ want) | (P1[3] ^ want)) == 0));
}

// Per-batch retry (rare): reissue just this batch, drain, recheck.
#define RETRY2(P0a, P1a, ap0_, ap1_) do { \
    if (!tags_ok2(P0a, P1a, want)) { \
      do { issue_pk2(ap0_, ap1_, P0a, P1a); WAITV("0"); } \
      while (!tags_ok2(P0a, P1a, want)); } } while (0)

__global__ __launch_bounds__(512, 2) void rnn_seq(
    const _Float16* __restrict__ Xh, const _Float16* __restrict__ Wp,
    const float* __restrict__ bg, const float* __restrict__ bih,
    const float* __restrict__ bhh, float* __restrict__ out,
    uint4v* __restrict__ Pk) {
  const int blk = blockIdx.x;          // 0..255
  const int g = blk >> 6;              // batch-row group 0..3 (rows g*16..+16)
  const int cb = blk & 63;             // column block 0..63
  const int tid = threadIdx.x;
  const int w = tid >> 6;              // wave 0..7 (K-split)
  const int lane = tid & 63;
  const int lrow = lane & 15;
  const int lkg = lane >> 4;
  const int phalf = lkg >> 1;          // which producer of the k-step pair
  const int odd = lkg & 1;             // which 8-col half
  const int wk = (w + cb) & 7;         // rotated h k-slice (r14 hotspot fix)
  const int pk0 = 3 * lrow + (odd ? 2 : 0);  // L1 packet index
  const int pk1 = 3 * lrow + 1;              // L2 packet index (shared)

  __shared__ float Red[8][80][18];               // 46,080 B (8 slabs, no add phase)
  __shared__ alignas(16) _Float16 Xstage[16 * 512];  // 16,384 B

  const int ej = tid & 15;
  const int rr = (tid >> 4) & 15;
  const int ghcol = cb * 16 + ej;
  const float bg_b  = bg[ghcol];
  const float br_b  = bih[ghcol] + bhh[ghcol];
  const float bz_b  = bih[HH + ghcol] + bhh[HH + ghcol];
  const float bin_b = bih[2 * HH + ghcol];
  const float bhn_b = bhh[2 * HH + ghcol];
  float hreg = 0.f;

  // producer block index for batch kk: p = pbase + kk*2
  const int pbase = wk * 8 + phalf;

  // register-resident weights (24 half8 = 96 VGPR); h-side uses wk
  half8 bx[3][2], b3[2], bh[3][4], b4[4];
#pragma unroll
  for (int tt = 0; tt < 3; ++tt)
#pragma unroll
    for (int kk = 0; kk < 2; ++kk)
      bx[tt][kk] = *(const half8*)(Wp + (size_t)(cb * 80 + tt * 16 + lrow) * KK + (w * 2 + kk) * 32 + lkg * 8);
#pragma unroll
  for (int kk = 0; kk < 2; ++kk)
    b3[kk] = *(const half8*)(Wp + (size_t)(cb * 80 + 48 + lrow) * KK + (w * 2 + kk) * 32 + lkg * 8);
#pragma unroll
  for (int tt = 0; tt < 3; ++tt)
#pragma unroll
    for (int kk = 0; kk < 4; ++kk)
      bh[tt][kk] = *(const half8*)(Wp + (size_t)(cb * 80 + tt * 16 + lrow) * KK + (16 + wk * 4 + kk) * 32 + lkg * 8);
#pragma unroll
  for (int kk = 0; kk < 4; ++kk)
    b4[kk] = *(const half8*)(Wp + (size_t)(cb * 80 + 64 + lrow) * KK + (16 + wk * 4 + kk) * 32 + lkg * 8);

  // prefetch Xstage(t=0)
#pragma unroll
  for (int kk = 0; kk < 2; ++kk) {
    const _Float16* gsrc = Xh + ((((size_t)0 * 16 + (w * 2 + kk)) * 64 + (g * RR + lrow)) * 4 + lkg) * 8;
    __builtin_amdgcn_global_load_lds(
        (const __attribute__((address_space(1))) void*)gsrc,
        (__attribute__((address_space(3))) void*)(Xstage + (w * 2 + kk) * 512), 16, 0, 0);
  }
  WAITV("0");

  for (int t = 0; t < SS; ++t) {
    const uint4v* Rg = Pk + (size_t)((g * 2 + (t & 1)) * 64) * PKST;
    uint4v* Rn = Pk + (size_t)((g * 2 + ((t + 1) & 1)) * 64) * PKST;
    const unsigned want = (unsigned)t;
    const uint4v* apA0 = Rg + (size_t)(pbase + 0) * PKST + pk0;
    const uint4v* apA1 = Rg + (size_t)(pbase + 0) * PKST + pk1;
    const uint4v* apB0 = Rg + (size_t)(pbase + 2) * PKST + pk0;
    const uint4v* apB1 = Rg + (size_t)(pbase + 2) * PKST + pk1;
    const uint4v* apC0 = Rg + (size_t)(pbase + 4) * PKST + pk0;
    const uint4v* apC1 = Rg + (size_t)(pbase + 4) * PKST + pk1;
    const uint4v* apD0 = Rg + (size_t)(pbase + 6) * PKST + pk0;
    const uint4v* apD1 = Rg + (size_t)(pbase + 6) * PKST + pk1;

    f32x4 zz = {0.f, 0.f, 0.f, 0.f};
    f32x4 acc[5];
#pragma unroll
    for (int tt = 0; tt < 5; ++tt) acc[tt] = zz;

    // ---- x ds_reads into registers ----
    half8 xfr[2];
#pragma unroll
    for (int kk = 0; kk < 2; ++kk)
      xfr[kk] = *(const half8*)(Xstage + (w * 2 + kk) * 512 + lane * 8);
    asm volatile("s_waitcnt lgkmcnt(0)" ::: "memory");   // reads retired (WAR)
    __builtin_amdgcn_sched_barrier(0);

    // ---- xpref(t+1) FIRST (its latency inside the A-wait = grace period) ----
    {
      const int tn = (t + 1 < SS) ? t + 1 : t;
#pragma unroll
      for (int kk = 0; kk < 2; ++kk) {
        const _Float16* gsrc = Xh + ((((size_t)tn * 16 + (w * 2 + kk)) * 64 + (g * RR + lrow)) * 4 + lkg) * 8;
        __builtin_amdgcn_global_load_lds(
            (const __attribute__((address_space(1))) void*)gsrc,
            (__attribute__((address_space(3))) void*)(Xstage + (w * 2 + kk) * 512), 16, 0, 0);
      }
    }

    // ---- issue all 4 packet batches; RTs overlap x-MFMA.
    // Queue/wave: [pub:1 (w<4,t>0)][xpref:2][A:2][B:2][C:2][D:2]
    uint4v A0, A1, B0, B1, C0, C1, D0, D1;
    issue_pk2(apA0, apA1, A0, A1);
    issue_pk2(apB0, apB1, B0, B1);
    issue_pk2(apC0, apC1, C0, C1);
    issue_pk2(apD0, apD1, D0, D1);

    // ---- x-MFMA from registers (overlaps packet round trips) ----
#pragma unroll
    for (int kk = 0; kk < 2; ++kk) {
      acc[0] = MFMA(xfr[kk], bx[0][kk], acc[0]);
      acc[1] = MFMA(xfr[kk], bx[1][kk], acc[1]);
      acc[2] = MFMA(xfr[kk], bx[2][kk], acc[2]);
      acc[3] = MFMA(xfr[kk], b3[kk], acc[3]);
    }

    // ---- h-MFMA: counted waits 6/4/2/0 + per-batch retry.
    // fv: even={P0.x,P0.y,P0.z,P1.x}; odd={P1.y,P1.z,P0.x,P0.y}
    WAITV("6"); RETRY2(A0, A1, apA0, apA1);
    {
      uint4v fv; fv[0] = odd ? A1[1] : A0[0]; fv[1] = odd ? A1[2] : A0[1];
      fv[2] = odd ? A0[0] : A0[2];     fv[3] = odd ? A0[1] : A1[0];
      half8 af = __builtin_bit_cast(half8, fv);
      acc[0] = MFMA(af, bh[0][0], acc[0]); acc[1] = MFMA(af, bh[1][0], acc[1]);
      acc[2] = MFMA(af, bh[2][0], acc[2]); acc[4] = MFMA(af, b4[0], acc[4]);
    }
    WAITV("4"); RETRY2(B0, B1, apB0, apB1);
    {
      uint4v fv; fv[0] = odd ? B1[1] : B0[0]; fv[1] = odd ? B1[2] : B0[1];
      fv[2] = odd ? B0[0] : B0[2];     fv[3] = odd ? B0[1] : B1[0];
      half8 af = __builtin_bit_cast(half8, fv);
      acc[0] = MFMA(af, bh[0][1], acc[0]); acc[1] = MFMA(af, bh[1][1], acc[1]);
      acc[2] = MFMA(af, bh[2][1], acc[2]); acc[4] = MFMA(af, b4[1], acc[4]);
    }
    WAITV("2"); RETRY2(C0, C1, apC0, apC1);
    {
      uint4v fv; fv[0] = odd ? C1[1] : C0[0]; fv[1] = odd ? C1[2] : C0[1];
      fv[2] = odd ? C0[0] : C0[2];     fv[3] = odd ? C0[1] : C1[0];
      half8 af = __builtin_bit_cast(half8, fv);
      acc[0] = MFMA(af, bh[0][2], acc[0]); acc[1] = MFMA(af, bh[1][2], acc[1]);
      acc[2] = MFMA(af, bh[2][2], acc[2]); acc[4] = MFMA(af, b4[2], acc[4]);
    }
    WAITV("0"); RETRY2(D0, D1, apD0, apD1);
    {
      uint4v fv; fv[0] = odd ? D1[1] : D0[0]; fv[1] = odd ? D1[2] : D0[1];
      fv[2] = odd ? D0[0] : D0[2];     fv[3] = odd ? D0[1] : D1[0];
      half8 af = __builtin_bit_cast(half8, fv);
      acc[0] = MFMA(af, bh[0][3], acc[0]); acc[1] = MFMA(af, bh[1][3], acc[1]);
      acc[2] = MFMA(af, bh[2][3], acc[2]); acc[4] = MFMA(af, b4[3], acc[4]);
    }

    // ---- 8-slab reduce: every wave writes its partials; ONE barrier ----
#pragma unroll
    for (int tt = 0; tt < 5; ++tt)
      *(f32x4*)&Red[w][tt * 16 + lrow][lkg * 4] = acc[tt];
    __syncthreads();

    // ---- fused epilogue + in-register packet publish (waves 0-3) ----
    if (tid < 256) {
      float s5[5];
#pragma unroll
      for (int g5 = 0; g5 < 5; ++g5) {
        float a = 0.f;
#pragma unroll
        for (int sl = 0; sl < 8; ++sl) a += Red[sl][g5 * 16 + ej][rr];
        s5[g5] = a;
      }
      float g_ = 1.f / (1.f + __expf(-(s5[0] + bg_b)));
      float r_ = 1.f / (1.f + __expf(-(s5[1] + br_b)));
      float z_ = 1.f / (1.f + __expf(-(s5[2] + bz_b)));
      float n_ = tanhf(s5[3] + bin_b + r_ * (s5[4] + bhn_b));
      float h = g_ * ((1.f - z_) * n_ + z_ * hreg);
      hreg = h;
      if (t == SS - 1) {
        out[(size_t)(g * RR + rr) * HH + ghcol] = h;
      } else {
        // pack col-pairs on even lanes, gather 3 dwords per packet into
        // publisher lanes 0..11 (packet w*12+lane), fire-and-forget store.
        unsigned hbits = (unsigned)__builtin_bit_cast(unsigned short, (_Float16)h);
        unsigned nb = (unsigned)__shfl_down((int)hbits, 1);
        int d = (int)(hbits | (nb << 16));          // valid on even cols
        int qp = lane / 3, sseg = lane - qp * 3;    // publisher mapping
        int srcbase = (qp << 4) + sseg * 6;
        int d0 = __builtin_amdgcn_ds_bpermute((srcbase + 0) << 2, d);
        int d1 = __builtin_amdgcn_ds_bpermute((srcbase + 2) << 2, d);
        int d2 = __builtin_amdgcn_ds_bpermute((srcbase + 4) << 2, d);
        if (lane < 12) {
          uint4v pk;
          pk[0] = (unsigned)d0;
          pk[1] = (unsigned)d1;
          pk[2] = (sseg == 2) ? 0u : (unsigned)d2;
          pk[3] = (unsigned)(t + 1);
          uint4v* dst = Rn + (size_t)cb * PKST + (w * 12 + lane);
          asm volatile("global_store_dwordx4 %0, %1, off sc0 sc1" :: "v"(dst), "v"(pk) : "memory");
        }
      }
    }
    __syncthreads();   // Red WAR + holds all waves until publish issued (r18)
  }
}

extern "C" void kernel_launch(void* const* d_in, const int* in_sizes, int n_in,
                              void* d_out, int out_size, void* d_ws, size_t ws_size,
                              hipStream_t stream) {
  const float* x   = (const float*)d_in[0];
  const float* Wg  = (const float*)d_in[1];
  const float* bg  = (const float*)d_in[2];
  const float* Wih = (const float*)d_in[3];
  const float* bih = (const float*)d_in[4];
  const float* Whh = (const float*)d_in[5];
  const float* bhh = (const float*)d_in[6];
  // d_in[7..10] (Wa, ba, Ws, bs) are mathematically dead: softmax over size-1 axis == 1
  float* out = (float*)d_out;

  char* ws = (char*)d_ws;
  _Float16* Wp = (_Float16*)ws;                        // 15,728,640 B
  _Float16* Xh = (_Float16*)(ws + 15728640);           // 33,554,432 B
  uint4v*   Pk = (uint4v*)(ws + 15728640 + 33554432);  // 4*2*64*48*16 = 393,216 B

  // Zero both parities every launch: tag 0 == valid zero h(0) for t=0; a
  // stale tag from a previous replay can never equal want=t>0 after the wipe.
  hipMemsetAsync((void*)Pk, 0, 393216, stream);
  prep_w<<<5120, 256, 0, stream>>>(Wg, Wih, Whh, Wp);
  prep_xh<<<dim3(512, 16), 256, 0, stream>>>(x, Xh);
  rnn_seq<<<256, 512, 0, stream>>>(Xh, Wp, bg, bih, bhh, out, Pk);
}